// Round 10
// baseline (254.952 us; speedup 1.0000x reference)
//
#include <hip/hip_runtime.h>

#define NB  4
#define CKQ 384
#define DH  128
#define HH  48
#define WW  64
#define HW  3072

#define NSPLIT 16
#define KSEG  (HW / NSPLIT)   // 192 keys per block
#define BQ 128                // queries per block (32 per wave, 4 waves)
#define BK 32                 // keys per tile
#define NIT (KSEG / BK)       // 6 tiles per block
#define VSP 40                // Vs row stride (bytes)
#define PTS 40                // Pt row stride (bytes)
#define XROW 136              // mconv staged row stride in u16 (272B)

typedef short bf16x8 __attribute__((ext_vector_type(8)));
typedef short b16x4  __attribute__((ext_vector_type(4)));
typedef float f32x4  __attribute__((ext_vector_type(4)));
typedef long  i64;
typedef long  i64x2 __attribute__((ext_vector_type(2)));
typedef unsigned short u16;
typedef unsigned int   u32;
typedef unsigned char  u8;
typedef unsigned long long u64;

__device__ __forceinline__ float b2f(u16 u){
  union { u32 i; float f; } x; x.i = ((u32)u) << 16; return x.f;
}
__device__ __forceinline__ u16 f2b(float f){
  union { float f; u32 i; } x; x.f = f;
  u32 r = (x.i + 0x7fffu + ((x.i >> 16) & 1u)) >> 16;
  return (u16)r;
}
__device__ __forceinline__ u8 f2f8(float f){
  return (u8)(__builtin_amdgcn_cvt_pk_fp8_f32(f, f, 0, false) & 0xff);
}

// ---------------------------------------------------------------------------
// Kernel P: fused prep. blocks [0,384): K/Q fp32->fp8 transpose;
// [384,600): conv-weight fragment prep; [600,984): val embed (16 d/block).
// block 256
// ---------------------------------------------------------------------------
__global__ __launch_bounds__(256)
void prep(const float* __restrict__ k, const float* __restrict__ q,
          const float* __restrict__ v, const float* __restrict__ wv,
          const float* __restrict__ w0, const float* __restrict__ w1,
          const float* __restrict__ w2,
          u8* __restrict__ kt8, u8* __restrict__ qt8, u8* __restrict__ val8,
          u16* __restrict__ o0, u16* __restrict__ o1, u16* __restrict__ o2){
  __shared__ u8 T[64][392];
  const int b   = blockIdx.x;
  const int tid = threadIdx.x;

  if (b < 384){
    // ---- tcast8: 64-p strip x full 384 c ----
    const int yy = b / 48;
    const int bx = b % 48;
    const float* in = (yy < NB) ? k : q;
    u8* outp        = (yy < NB) ? kt8 : qt8;
    const int n  = yy & (NB - 1);
    const int p0 = bx * 64;
    const int tx = tid & 63;
    const int ty = tid >> 6;
    const float* ib = in + (size_t)n * CKQ * HW + p0;
    #pragma unroll 8
    for (int c = ty; c < CKQ; c += 4)
      T[tx][c] = f2f8(ib[(size_t)c * HW + tx]);
    __syncthreads();
    u8* ob = outp + ((size_t)n * HW + p0) * CKQ;
    #pragma unroll
    for (int it = 0; it < 12; ++it){
      int ch  = it * 256 + tid;
      int row = ch / 48;
      int g   = ch - row * 48;
      *(u64*)(ob + (size_t)row * CKQ + g * 8) = *(const u64*)&T[row][g * 8];
    }
  } else if (b < 600){
    // ---- wprep: fp32 OIHW -> bf16 A-fragment stream ----
    const int bb = b - 384;          // 216 = 72 x 3
    const int bx = bb % 72;
    const int wy = bb / 72;
    const float* w = (wy == 0) ? w0 : (wy == 1) ? w1 : w2;
    u16* wt        = (wy == 0) ? o0 : (wy == 1) ? o1 : o2;
    int g    = bx * 256 + tid;
    int fid  = g >> 6;
    int lane = g & 63;
    int l15  = lane & 15, quad = lane >> 4;
    int tap  = fid >> 5;
    int cst  = (fid >> 3) & 3;
    int dt   = fid & 7;
    int d    = dt * 16 + l15;
    u16* dst = wt + (size_t)fid * 512 + lane * 8;
    #pragma unroll
    for (int e = 0; e < 8; ++e){
      int c = cst * 32 + quad * 8 + e;
      dst[e] = f2b(w[((size_t)d * DH + c) * 9 + tap]);
    }
  } else {
    // ---- val embed: 16 d x 256 p per block, 8 loads in flight ----
    const int bb = b - 600;          // 384 = 12 x 8 x 4
    const int px = bb % 12;
    const int db = (bb / 12) & 7;
    const int n  = bb / 96;
    const int p  = px * 256 + tid;
    const int d0 = db * 16;
    const float* vb = v + (size_t)n * DH * HW;
    float acc[16];
    #pragma unroll
    for (int dd = 0; dd < 16; ++dd) acc[dd] = 0.f;
    #pragma unroll 8
    for (int c = 0; c < DH; ++c){
      float vv = vb[(size_t)c * HW + p];
      #pragma unroll
      for (int dd = 0; dd < 16; ++dd)
        acc[dd] += wv[(d0 + dd) * DH + c] * vv;
    }
    u8* ob = val8 + (size_t)n * DH * HW;
    #pragma unroll
    for (int dd = 0; dd < 16; ++dd)
      ob[(size_t)(d0 + dd) * HW + p] = f2f8(acc[dd]);
  }
}

// ---------------------------------------------------------------------------
// Kernel B: split-K flash attention, fp8 operands, DOUBLE-BUFFERED K/V LDS.
// Tile t+1's global loads issue at the top of iter t; the vmcnt wait sits in
// the LDS write placed AFTER compute -> global latency overlaps a full iter.
// One __syncthreads per iter. LDS 39KB -> 3 blocks/CU; VGPR ~100.
// grid (24, NSPLIT, 4) block 256
// ---------------------------------------------------------------------------
__global__ __launch_bounds__(256, 3)
void attn8(const u8* __restrict__ kt, const u8* __restrict__ qt,
           const u8* __restrict__ val, u16* __restrict__ outp,
           float* __restrict__ lsum){
  __shared__ u8 Ks[2][BK * CKQ];   // 2 x 12 KB
  __shared__ u8 Vs[2][DH * VSP];   // 2 x 5 KB
  __shared__ u8 Pt[BQ * PTS];      // 5 KB

  const int tid  = threadIdx.x;
  const int wv   = tid >> 6;
  const int lane = tid & 63;
  const int quad = lane >> 4;
  const int l15  = lane & 15;
  const int n    = blockIdx.z;
  const int seg  = blockIdx.y;
  const int j0   = blockIdx.x * BQ;
  const int jra  = wv * 32 + l15;
  const int jrb  = jra + 16;
  const int ja   = j0 + jra;
  const int jb   = j0 + jrb;

  const u8* ktb = kt  + (size_t)n * CKQ * HW;
  const u8* vb  = val + (size_t)n * DH * HW;

  // per-thread staging slices: K 3x16B chunks (of BK*24), V 2x8B (of DH*4)
  const int ki0 = tid, ki1 = tid + 256, ki2 = tid + 512;
  const int vi0 = tid, vi1 = tid + 256;

  const u8* qrowa = qt + ((size_t)n * HW + ja) * CKQ;
  const u8* qrowb = qt + ((size_t)n * HW + jb) * CKQ;
  i64 qfa[12], qfb[12];
  #pragma unroll
  for (int cs = 0; cs < 12; ++cs){
    qfa[cs] = *(const i64*)&qrowa[cs * 32 + quad * 8];
    qfb[cs] = *(const i64*)&qrowb[cs * 32 + quad * 8];
  }

  const f32x4 zero = {0.f, 0.f, 0.f, 0.f};
  f32x4 oa[8], obacc[8];
  #pragma unroll
  for (int i = 0; i < 8; ++i){ oa[i] = zero; obacc[i] = zero; }
  float la = 0.f, lbv = 0.f;

  const float scale = 0.05103103630798287f;  // 1/sqrt(384)

  // ---- stage tile 0 into buffer 0 ----
  i64x2 kr0, kr1, kr2; i64 vr0, vr1;
  {
    const int i0 = seg * KSEG;
    kr0 = *(const i64x2*)&ktb[(size_t)(i0 + ki0 / 24) * CKQ + (ki0 % 24) * 16];
    kr1 = *(const i64x2*)&ktb[(size_t)(i0 + ki1 / 24) * CKQ + (ki1 % 24) * 16];
    kr2 = *(const i64x2*)&ktb[(size_t)(i0 + ki2 / 24) * CKQ + (ki2 % 24) * 16];
    vr0 = *(const i64*)&vb[(size_t)(vi0 >> 2) * HW + i0 + (vi0 & 3) * 8];
    vr1 = *(const i64*)&vb[(size_t)(vi1 >> 2) * HW + i0 + (vi1 & 3) * 8];
  }
  #pragma unroll
  for (int r = 0; r < 3; ++r){
    int idx = tid + r * 256;
    int i = idx / 24, g2 = idx % 24;
    int g0 = 2 * g2, g1 = g0 + 1;
    int gs0 = (g0 & ~7) | ((g0 ^ i) & 7);
    int gs1 = (g1 & ~7) | ((g1 ^ i) & 7);
    i64x2 dv = (r == 0) ? kr0 : (r == 1) ? kr1 : kr2;
    *(i64*)&Ks[0][i * CKQ + gs0 * 8] = dv[0];
    *(i64*)&Ks[0][i * CKQ + gs1 * 8] = dv[1];
  }
  *(i64*)&Vs[0][(vi0 >> 2) * VSP + (vi0 & 3) * 8] = vr0;
  *(i64*)&Vs[0][(vi1 >> 2) * VSP + (vi1 & 3) * 8] = vr1;
  __syncthreads();

  for (int it = 0; it < NIT; ++it){
    const int cur = it & 1, nxt = cur ^ 1;
    const bool more = (it + 1 < NIT);

    // issue next tile's global loads NOW; latency overlaps this iter's compute
    if (more){
      const int i0n = seg * KSEG + (it + 1) * BK;
      kr0 = *(const i64x2*)&ktb[(size_t)(i0n + ki0 / 24) * CKQ + (ki0 % 24) * 16];
      kr1 = *(const i64x2*)&ktb[(size_t)(i0n + ki1 / 24) * CKQ + (ki1 % 24) * 16];
      kr2 = *(const i64x2*)&ktb[(size_t)(i0n + ki2 / 24) * CKQ + (ki2 % 24) * 16];
      vr0 = *(const i64*)&vb[(size_t)(vi0 >> 2) * HW + i0n + (vi0 & 3) * 8];
      vr1 = *(const i64*)&vb[(size_t)(vi1 >> 2) * HW + i0n + (vi1 & 3) * 8];
    }

    // S = K^T Q  (2 key-subtiles x 12 c-steps; a0/a1 shared by both j-sets)
    f32x4 s0a = zero, s1a = zero, s0b = zero, s1b = zero;
    #pragma unroll
    for (int cs = 0; cs < 12; ++cs){
      int g  = 4 * cs + quad;
      int gs = (g & ~7) | ((g ^ l15) & 7);
      i64 a0 = *(const i64*)&Ks[cur][l15 * CKQ + gs * 8];
      i64 a1 = *(const i64*)&Ks[cur][(16 + l15) * CKQ + gs * 8];
      s0a = __builtin_amdgcn_mfma_f32_16x16x32_fp8_fp8(a0, qfa[cs], s0a, 0, 0, 0);
      s1a = __builtin_amdgcn_mfma_f32_16x16x32_fp8_fp8(a1, qfa[cs], s1a, 0, 0, 0);
      s0b = __builtin_amdgcn_mfma_f32_16x16x32_fp8_fp8(a0, qfb[cs], s0b, 0, 0, 0);
      s1b = __builtin_amdgcn_mfma_f32_16x16x32_fp8_fp8(a1, qfb[cs], s1b, 0, 0, 0);
    }

    float pa[8], pb[8]; float tsa = 0.f, tsb = 0.f;
    #pragma unroll
    for (int r = 0; r < 4; ++r){
      pa[r]     = __expf(s0a[r] * scale);
      pa[4 + r] = __expf(s1a[r] * scale);
      pb[r]     = __expf(s0b[r] * scale);
      pb[4 + r] = __expf(s1b[r] * scale);
    }
    #pragma unroll
    for (int i = 0; i < 8; ++i){ tsa += pa[i]; tsb += pb[i]; }
    la += tsa; lbv += tsb;

    u32 wa0 = __builtin_amdgcn_cvt_pk_fp8_f32(pa[0], pa[1], 0, false);
    wa0     = __builtin_amdgcn_cvt_pk_fp8_f32(pa[2], pa[3], wa0, true);
    u32 wa1 = __builtin_amdgcn_cvt_pk_fp8_f32(pa[4], pa[5], 0, false);
    wa1     = __builtin_amdgcn_cvt_pk_fp8_f32(pa[6], pa[7], wa1, true);
    u32 wb0 = __builtin_amdgcn_cvt_pk_fp8_f32(pb[0], pb[1], 0, false);
    wb0     = __builtin_amdgcn_cvt_pk_fp8_f32(pb[2], pb[3], wb0, true);
    u32 wb1 = __builtin_amdgcn_cvt_pk_fp8_f32(pb[4], pb[5], 0, false);
    wb1     = __builtin_amdgcn_cvt_pk_fp8_f32(pb[6], pb[7], wb1, true);
    *(u32*)&Pt[jra * PTS + quad * 4]      = wa0;
    *(u32*)&Pt[jra * PTS + 16 + quad * 4] = wa1;
    *(u32*)&Pt[jrb * PTS + quad * 4]      = wb0;
    *(u32*)&Pt[jrb * PTS + 16 + quad * 4] = wb1;
    __builtin_amdgcn_wave_barrier();

    i64 bpa = *(const i64*)&Pt[jra * PTS + quad * 8];
    i64 bpb = *(const i64*)&Pt[jrb * PTS + quad * 8];
    #pragma unroll
    for (int dt = 0; dt < 8; ++dt){
      i64 av = *(const i64*)&Vs[cur][(dt * 16 + l15) * VSP + quad * 8];
      oa[dt]    = __builtin_amdgcn_mfma_f32_16x16x32_fp8_fp8(av, bpa, oa[dt], 0, 0, 0);
      obacc[dt] = __builtin_amdgcn_mfma_f32_16x16x32_fp8_fp8(av, bpb, obacc[dt], 0, 0, 0);
    }

    // write prefetched regs -> other buffer (vmcnt wait lands here, post-compute)
    if (more){
      #pragma unroll
      for (int r = 0; r < 3; ++r){
        int idx = tid + r * 256;
        int i = idx / 24, g2 = idx % 24;
        int g0 = 2 * g2, g1 = g0 + 1;
        int gs0 = (g0 & ~7) | ((g0 ^ i) & 7);
        int gs1 = (g1 & ~7) | ((g1 ^ i) & 7);
        i64x2 dv = (r == 0) ? kr0 : (r == 1) ? kr1 : kr2;
        *(i64*)&Ks[nxt][i * CKQ + gs0 * 8] = dv[0];
        *(i64*)&Ks[nxt][i * CKQ + gs1 * 8] = dv[1];
      }
      *(i64*)&Vs[nxt][(vi0 >> 2) * VSP + (vi0 & 3) * 8] = vr0;
      *(i64*)&Vs[nxt][(vi1 >> 2) * VSP + (vi1 & 3) * 8] = vr1;
    }
    __syncthreads();
  }

  la  += __shfl_xor(la, 16);  la  += __shfl_xor(la, 32);
  lbv += __shfl_xor(lbv, 16); lbv += __shfl_xor(lbv, 32);

  u16* obp = outp + ((size_t)(seg * NB + n) * HW) * DH;
  #pragma unroll
  for (int dt = 0; dt < 8; ++dt){
    b16x4 pka = { (short)f2b(oa[dt][0]), (short)f2b(oa[dt][1]),
                  (short)f2b(oa[dt][2]), (short)f2b(oa[dt][3]) };
    b16x4 pkb = { (short)f2b(obacc[dt][0]), (short)f2b(obacc[dt][1]),
                  (short)f2b(obacc[dt][2]), (short)f2b(obacc[dt][3]) };
    *(b16x4*)&obp[(size_t)ja * DH + dt * 16 + quad * 4] = pka;
    *(b16x4*)&obp[(size_t)jb * DH + dt * 16 + quad * 4] = pkb;
  }
  if (quad == 0){
    lsum[(size_t)(seg * NB + n) * HW + ja] = la;
    lsum[(size_t)(seg * NB + n) * HW + jb] = lbv;
  }
}

// ---------------------------------------------------------------------------
// Kernel B2: pval_t[n][j][d] = (sum_s o_s) / (sum_s l_s)
// ---------------------------------------------------------------------------
__global__ __launch_bounds__(256)
void combine(const u16* __restrict__ ob, const float* __restrict__ lb,
             u16* __restrict__ pval_t){
  size_t flat = (size_t)blockIdx.x * 256 + threadIdx.x;
  int d = (int)(flat & 127);
  size_t nj = flat >> 7;
  int j = (int)(nj % HW);
  int n = (int)(nj / HW);
  float acc = 0.f, ls = 0.f;
  #pragma unroll
  for (int s = 0; s < NSPLIT; ++s){
    acc += b2f(ob[((size_t)(s * NB + n) * HW + j) * DH + d]);
    ls  += lb[(size_t)(s * NB + n) * HW + j];
  }
  pval_t[flat] = f2b(acc / ls);
}

// ---------------------------------------------------------------------------
// Kernel C: LDS-staged MFMA implicit-GEMM 3x3 conv (R8-proven body).
// grid (48, 4, NB) block 256, 3 blocks/CU.
// ---------------------------------------------------------------------------
template<int DIL, int RESM, int OUTM>
__global__ __launch_bounds__(256, 3)
void mconv(const u16* __restrict__ in_t, const u16* __restrict__ wtf,
           const void* __restrict__ res, void* __restrict__ out){
  __shared__ u16 Xs[3 * 64 * XROW];   // 52224 B

  const int tid  = threadIdx.x;
  const int w    = tid >> 6;
  const int lane = tid & 63;
  const int quad = lane >> 4;
  const int l15  = lane & 15;
  const int n    = blockIdx.z;
  const int y    = blockIdx.x;
  const int by   = blockIdx.y;
  const int xw   = w * 16;

  const bf16x8 bz8 = {0,0,0,0,0,0,0,0};
  #pragma unroll
  for (int yi = 0; yi < 3; ++yi){
    int ysrc = y + (yi - 1) * DIL;
    bool ok = (unsigned)ysrc < (unsigned)HH;
    #pragma unroll
    for (int pass = 0; pass < 4; ++pass){
      int ch = pass * 256 + tid;
      int x  = ch >> 4;
      int g  = ch & 15;
      bf16x8 vv = bz8;
      if (ok)
        vv = *(const bf16x8*)&in_t[((size_t)n * HW + ysrc * WW + x) * DH + g * 8];
      *(bf16x8*)&Xs[(yi * 64 + x) * XROW + g * 8] = vv;
    }
  }
  __syncthreads();

  f32x4 acc[2];
  acc[0] = (f32x4){0.f, 0.f, 0.f, 0.f};
  acc[1] = (f32x4){0.f, 0.f, 0.f, 0.f};

  #pragma unroll
  for (int tap = 0; tap < 9; ++tap){
    const int yi = tap / 3;
    const int dx = (tap % 3 - 1) * DIL;
    const int xp = xw + l15 + dx;
    const bool vx = (unsigned)xp < (unsigned)WW;
    const int xc = vx ? xp : 0;
    const u16* xrow = &Xs[(yi * 64 + xc) * XROW];
    #pragma unroll
    for (int cst = 0; cst < 4; ++cst){
      bf16x8 bf = bz8;
      if (vx) bf = *(const bf16x8*)&xrow[cst * 32 + quad * 8];
      #pragma unroll
      for (int dt = 0; dt < 2; ++dt){
        int fid = (tap * 4 + cst) * 8 + by * 2 + dt;
        bf16x8 af = *(const bf16x8*)&wtf[(size_t)fid * 512 + lane * 8];
        acc[dt] = __builtin_amdgcn_mfma_f32_16x16x32_bf16(af, bf, acc[dt], 0, 0, 0);
      }
    }
  }

  const int p = y * WW + xw + l15;
  #pragma unroll
  for (int dt = 0; dt < 2; ++dt){
    const int d0q = by * 32 + dt * 16 + quad * 4;
    float v4[4];
    #pragma unroll
    for (int r = 0; r < 4; ++r){
      float vv = acc[dt][r];
      vv = (vv >= 0.f) ? vv : 0.2f * vv;
      if (RESM == 1)
        vv += ((const float*)res)[((size_t)n * DH + d0q + r) * HW + p];
      v4[r] = vv;
    }
    if (RESM == 2){
      b16x4 rv = *(const b16x4*)&((const u16*)res)[((size_t)n * HW + p) * DH + d0q];
      #pragma unroll
      for (int r = 0; r < 4; ++r) v4[r] += b2f((u16)rv[r]);
    }
    if (OUTM == 0){
      b16x4 pk = { (short)f2b(v4[0]), (short)f2b(v4[1]),
                   (short)f2b(v4[2]), (short)f2b(v4[3]) };
      *(b16x4*)&((u16*)out)[((size_t)n * HW + p) * DH + d0q] = pk;
    } else {
      #pragma unroll
      for (int r = 0; r < 4; ++r)
        ((float*)out)[((size_t)n * DH + d0q + r) * HW + p] = v4[r];
    }
  }
}

// ---------------------------------------------------------------------------
extern "C" void kernel_launch(void* const* d_in, const int* in_sizes, int n_in,
                              void* d_out, int out_size, void* d_ws, size_t ws_size,
                              hipStream_t stream){
  const float* k    = (const float*)d_in[0];
  const float* q    = (const float*)d_in[1];
  const float* v    = (const float*)d_in[2];
  const float* wv   = (const float*)d_in[3];
  const float* wout = (const float*)d_in[4];
  const float* wff1 = (const float*)d_in[5];
  const float* wff2 = (const float*)d_in[6];
  float* out = (float*)d_out;

  const size_t TEN  = (size_t)NB * DH * HW;    // 1,572,864
  const size_t KTEN = (size_t)NB * CKQ * HW;   // 4,718,592
  const size_t WT   = (size_t)9 * DH * DH;     // 147,456
  u8*  kt8    = (u8*)d_ws;
  u8*  qt8    = kt8 + KTEN;
  u8*  val8   = qt8 + KTEN;
  u16* wt1    = (u16*)(val8 + TEN);
  u16* wt2    = wt1 + WT;
  u16* wt3    = wt2 + WT;
  u16* pval_t = wt3 + WT;
  u16* v2_t   = pval_t + TEN;
  u16* tmid_t = v2_t + TEN;
  u16* ob     = tmid_t + TEN;                  // NSPLIT*TEN bf16
  float* lb   = (float*)(ob + (size_t)NSPLIT * TEN);

  prep   <<<dim3(984), 256, 0, stream>>>(k, q, v, wv, wout, wff1, wff2,
                                         kt8, qt8, val8, wt1, wt2, wt3);
  attn8  <<<dim3(HW / BQ, NSPLIT, NB), 256, 0, stream>>>(kt8, qt8, val8, ob, lb);
  combine<<<dim3((unsigned)(TEN / 256)), 256, 0, stream>>>(ob, lb, pval_t);
  mconv<1, 1, 0><<<dim3(48, 4, NB), 256, 0, stream>>>(pval_t, wt1, (const void*)v,    (void*)v2_t);
  mconv<2, 0, 0><<<dim3(48, 4, NB), 256, 0, stream>>>(v2_t,   wt2, (const void*)nullptr, (void*)tmid_t);
  mconv<1, 2, 1><<<dim3(48, 4, NB), 256, 0, stream>>>(tmid_t, wt3, (const void*)v2_t, (void*)out);
}

// Round 11
// 231.742 us; speedup vs baseline: 1.1002x; 1.1002x over previous
//
#include <hip/hip_runtime.h>

#define NB  4
#define CKQ 384
#define DH  128
#define HH  48
#define WW  64
#define HW  3072

#define NSPLIT 16
#define KSEG  (HW / NSPLIT)   // 192 keys per block
#define BQ 128                // queries per block (32 per wave, 4 waves)
#define BK 32                 // keys per tile
#define VSP 40                // Vs row stride (bytes)
#define PTS 40                // Pt row stride (bytes)
#define XROW 136              // mconv staged row stride in u16 (272B)

typedef short bf16x8 __attribute__((ext_vector_type(8)));
typedef short b16x4  __attribute__((ext_vector_type(4)));
typedef float f32x4  __attribute__((ext_vector_type(4)));
typedef long  i64;
typedef long  i64x2 __attribute__((ext_vector_type(2)));
typedef unsigned short u16;
typedef unsigned int   u32;
typedef unsigned char  u8;
typedef unsigned long long u64;

__device__ __forceinline__ float b2f(u16 u){
  union { u32 i; float f; } x; x.i = ((u32)u) << 16; return x.f;
}
__device__ __forceinline__ u16 f2b(float f){
  union { float f; u32 i; } x; x.f = f;
  u32 r = (x.i + 0x7fffu + ((x.i >> 16) & 1u)) >> 16;
  return (u16)r;
}
__device__ __forceinline__ u8 f2f8(float f){
  return (u8)(__builtin_amdgcn_cvt_pk_fp8_f32(f, f, 0, false) & 0xff);
}

// ---------------------------------------------------------------------------
// Kernel P: fused prep. blocks [0,384): K/Q fp32->fp8 transpose;
// [384,600): conv-weight fragment prep; [600,984): val embed (16 d/block).
// block 256
// ---------------------------------------------------------------------------
__global__ __launch_bounds__(256)
void prep(const float* __restrict__ k, const float* __restrict__ q,
          const float* __restrict__ v, const float* __restrict__ wv,
          const float* __restrict__ w0, const float* __restrict__ w1,
          const float* __restrict__ w2,
          u8* __restrict__ kt8, u8* __restrict__ qt8, u8* __restrict__ val8,
          u16* __restrict__ o0, u16* __restrict__ o1, u16* __restrict__ o2){
  __shared__ u8 T[64][392];
  const int b   = blockIdx.x;
  const int tid = threadIdx.x;

  if (b < 384){
    // ---- tcast8: 64-p strip x full 384 c, 8 loads in flight ----
    const int yy = b / 48;
    const int bx = b % 48;
    const float* in = (yy < NB) ? k : q;
    u8* outp        = (yy < NB) ? kt8 : qt8;
    const int n  = yy & (NB - 1);
    const int p0 = bx * 64;
    const int tx = tid & 63;
    const int ty = tid >> 6;
    const float* ib = in + (size_t)n * CKQ * HW + p0;
    #pragma unroll 8
    for (int c = ty; c < CKQ; c += 4)
      T[tx][c] = f2f8(ib[(size_t)c * HW + tx]);
    __syncthreads();
    u8* ob = outp + ((size_t)n * HW + p0) * CKQ;
    #pragma unroll
    for (int it = 0; it < 12; ++it){
      int ch  = it * 256 + tid;
      int row = ch / 48;
      int g   = ch - row * 48;
      *(u64*)(ob + (size_t)row * CKQ + g * 8) = *(const u64*)&T[row][g * 8];
    }
  } else if (b < 600){
    // ---- wprep: fp32 OIHW -> bf16 A-fragment stream ----
    const int bb = b - 384;          // 216 = 72 x 3
    const int bx = bb % 72;
    const int wy = bb / 72;
    const float* w = (wy == 0) ? w0 : (wy == 1) ? w1 : w2;
    u16* wt        = (wy == 0) ? o0 : (wy == 1) ? o1 : o2;
    int g    = bx * 256 + tid;
    int fid  = g >> 6;
    int lane = g & 63;
    int l15  = lane & 15, quad = lane >> 4;
    int tap  = fid >> 5;
    int cst  = (fid >> 3) & 3;
    int dt   = fid & 7;
    int d    = dt * 16 + l15;
    u16* dst = wt + (size_t)fid * 512 + lane * 8;
    #pragma unroll
    for (int e = 0; e < 8; ++e){
      int c = cst * 32 + quad * 8 + e;
      dst[e] = f2b(w[((size_t)d * DH + c) * 9 + tap]);
    }
  } else {
    // ---- val embed: 16 d x 256 p per block, 8 loads in flight ----
    const int bb = b - 600;          // 384 = 12 x 8 x 4
    const int px = bb % 12;
    const int db = (bb / 12) & 7;
    const int n  = bb / 96;
    const int p  = px * 256 + tid;
    const int d0 = db * 16;
    const float* vb = v + (size_t)n * DH * HW;
    float acc[16];
    #pragma unroll
    for (int dd = 0; dd < 16; ++dd) acc[dd] = 0.f;
    #pragma unroll 8
    for (int c = 0; c < DH; ++c){
      float vv = vb[(size_t)c * HW + p];
      #pragma unroll
      for (int dd = 0; dd < 16; ++dd)
        acc[dd] += wv[(d0 + dd) * DH + c] * vv;
    }
    u8* ob = val8 + (size_t)n * DH * HW;
    #pragma unroll
    for (int dd = 0; dd < 16; ++dd)
      ob[(size_t)(d0 + dd) * HW + p] = f2f8(acc[dd]);
  }
}

// ---------------------------------------------------------------------------
// Kernel B: split-K flash attention, fp8 operands (R8-proven single-buffer
// body -- dbuf/reg-prefetch both regress via scratch spill, see R7/R10).
// grid (24, NSPLIT, 4) block 256, 3 blocks/CU
// ---------------------------------------------------------------------------
__global__ __launch_bounds__(256, 3)
void attn8(const u8* __restrict__ kt, const u8* __restrict__ qt,
           const u8* __restrict__ val, u16* __restrict__ outp,
           float* __restrict__ lsum){
  __shared__ u8 Ks[BK * CKQ];     // 12 KB
  __shared__ u8 Vs[DH * VSP];     // 5 KB
  __shared__ u8 Pt[BQ * PTS];     // 5 KB

  const int tid  = threadIdx.x;
  const int wv   = tid >> 6;
  const int lane = tid & 63;
  const int quad = lane >> 4;
  const int l15  = lane & 15;
  const int n    = blockIdx.z;
  const int seg  = blockIdx.y;
  const int j0   = blockIdx.x * BQ;
  const int jra  = wv * 32 + l15;
  const int jrb  = jra + 16;
  const int ja   = j0 + jra;
  const int jb   = j0 + jrb;

  const u8* qrowa = qt + ((size_t)n * HW + ja) * CKQ;
  const u8* qrowb = qt + ((size_t)n * HW + jb) * CKQ;
  i64 qfa[12], qfb[12];
  #pragma unroll
  for (int cs = 0; cs < 12; ++cs){
    qfa[cs] = *(const i64*)&qrowa[cs * 32 + quad * 8];
    qfb[cs] = *(const i64*)&qrowb[cs * 32 + quad * 8];
  }

  const f32x4 zero = {0.f, 0.f, 0.f, 0.f};
  f32x4 oa[8], obacc[8];
  #pragma unroll
  for (int i = 0; i < 8; ++i){ oa[i] = zero; obacc[i] = zero; }
  float la = 0.f, lbv = 0.f;

  const u8* ktb = kt  + (size_t)n * CKQ * HW;
  const u8* vb  = val + (size_t)n * DH * HW;
  const float scale = 0.05103103630798287f;  // 1/sqrt(384)

  for (int it = 0; it < KSEG / BK; ++it){
    const int i0 = seg * KSEG + it * BK;
    for (int idx = tid; idx < BK * 24; idx += 256){
      int i  = idx / 24;
      int g2 = idx % 24;
      i64x2 dv = *(const i64x2*)&ktb[(size_t)(i0 + i) * CKQ + g2 * 16];
      int g0 = 2 * g2, g1 = g0 + 1;
      int gs0 = (g0 & ~7) | ((g0 ^ i) & 7);
      int gs1 = (g1 & ~7) | ((g1 ^ i) & 7);
      *(i64*)&Ks[i * CKQ + gs0 * 8] = dv[0];
      *(i64*)&Ks[i * CKQ + gs1 * 8] = dv[1];
    }
    for (int idx = tid; idx < DH * 4; idx += 256){
      int dd = idx >> 2;
      int c8 = idx & 3;
      *(i64*)&Vs[dd * VSP + c8 * 8] = *(const i64*)&vb[(size_t)dd * HW + i0 + c8 * 8];
    }
    __syncthreads();

    f32x4 s0a = zero, s1a = zero, s0b = zero, s1b = zero;
    #pragma unroll
    for (int cs = 0; cs < 12; ++cs){
      int g  = 4 * cs + quad;
      int gs = (g & ~7) | ((g ^ l15) & 7);
      i64 a0 = *(const i64*)&Ks[l15 * CKQ + gs * 8];
      i64 a1 = *(const i64*)&Ks[(16 + l15) * CKQ + gs * 8];
      s0a = __builtin_amdgcn_mfma_f32_16x16x32_fp8_fp8(a0, qfa[cs], s0a, 0, 0, 0);
      s1a = __builtin_amdgcn_mfma_f32_16x16x32_fp8_fp8(a1, qfa[cs], s1a, 0, 0, 0);
      s0b = __builtin_amdgcn_mfma_f32_16x16x32_fp8_fp8(a0, qfb[cs], s0b, 0, 0, 0);
      s1b = __builtin_amdgcn_mfma_f32_16x16x32_fp8_fp8(a1, qfb[cs], s1b, 0, 0, 0);
    }

    float pa[8], pb[8]; float tsa = 0.f, tsb = 0.f;
    #pragma unroll
    for (int r = 0; r < 4; ++r){
      pa[r]     = __expf(s0a[r] * scale);
      pa[4 + r] = __expf(s1a[r] * scale);
      pb[r]     = __expf(s0b[r] * scale);
      pb[4 + r] = __expf(s1b[r] * scale);
    }
    #pragma unroll
    for (int i = 0; i < 8; ++i){ tsa += pa[i]; tsb += pb[i]; }
    la += tsa; lbv += tsb;

    u32 wa0 = __builtin_amdgcn_cvt_pk_fp8_f32(pa[0], pa[1], 0, false);
    wa0     = __builtin_amdgcn_cvt_pk_fp8_f32(pa[2], pa[3], wa0, true);
    u32 wa1 = __builtin_amdgcn_cvt_pk_fp8_f32(pa[4], pa[5], 0, false);
    wa1     = __builtin_amdgcn_cvt_pk_fp8_f32(pa[6], pa[7], wa1, true);
    u32 wb0 = __builtin_amdgcn_cvt_pk_fp8_f32(pb[0], pb[1], 0, false);
    wb0     = __builtin_amdgcn_cvt_pk_fp8_f32(pb[2], pb[3], wb0, true);
    u32 wb1 = __builtin_amdgcn_cvt_pk_fp8_f32(pb[4], pb[5], 0, false);
    wb1     = __builtin_amdgcn_cvt_pk_fp8_f32(pb[6], pb[7], wb1, true);
    *(u32*)&Pt[jra * PTS + quad * 4]      = wa0;
    *(u32*)&Pt[jra * PTS + 16 + quad * 4] = wa1;
    *(u32*)&Pt[jrb * PTS + quad * 4]      = wb0;
    *(u32*)&Pt[jrb * PTS + 16 + quad * 4] = wb1;
    __builtin_amdgcn_wave_barrier();

    i64 bpa = *(const i64*)&Pt[jra * PTS + quad * 8];
    i64 bpb = *(const i64*)&Pt[jrb * PTS + quad * 8];
    #pragma unroll
    for (int dt = 0; dt < 8; ++dt){
      i64 av = *(const i64*)&Vs[(dt * 16 + l15) * VSP + quad * 8];
      oa[dt]    = __builtin_amdgcn_mfma_f32_16x16x32_fp8_fp8(av, bpa, oa[dt], 0, 0, 0);
      obacc[dt] = __builtin_amdgcn_mfma_f32_16x16x32_fp8_fp8(av, bpb, obacc[dt], 0, 0, 0);
    }
    __syncthreads();
  }

  la  += __shfl_xor(la, 16);  la  += __shfl_xor(la, 32);
  lbv += __shfl_xor(lbv, 16); lbv += __shfl_xor(lbv, 32);

  u16* obp = outp + ((size_t)(seg * NB + n) * HW) * DH;
  #pragma unroll
  for (int dt = 0; dt < 8; ++dt){
    b16x4 pka = { (short)f2b(oa[dt][0]), (short)f2b(oa[dt][1]),
                  (short)f2b(oa[dt][2]), (short)f2b(oa[dt][3]) };
    b16x4 pkb = { (short)f2b(obacc[dt][0]), (short)f2b(obacc[dt][1]),
                  (short)f2b(obacc[dt][2]), (short)f2b(obacc[dt][3]) };
    *(b16x4*)&obp[(size_t)ja * DH + dt * 16 + quad * 4] = pka;
    *(b16x4*)&obp[(size_t)jb * DH + dt * 16 + quad * 4] = pkb;
  }
  if (quad == 0){
    lsum[(size_t)(seg * NB + n) * HW + ja] = la;
    lsum[(size_t)(seg * NB + n) * HW + jb] = lbv;
  }
}

// ---------------------------------------------------------------------------
// Kernel B2: pval_t[n][j][d] = (sum_s o_s) / (sum_s l_s)
// ---------------------------------------------------------------------------
__global__ __launch_bounds__(256)
void combine(const u16* __restrict__ ob, const float* __restrict__ lb,
             u16* __restrict__ pval_t){
  size_t flat = (size_t)blockIdx.x * 256 + threadIdx.x;
  int d = (int)(flat & 127);
  size_t nj = flat >> 7;
  int j = (int)(nj % HW);
  int n = (int)(nj / HW);
  float acc = 0.f, ls = 0.f;
  #pragma unroll
  for (int s = 0; s < NSPLIT; ++s){
    acc += b2f(ob[((size_t)(s * NB + n) * HW + j) * DH + d]);
    ls  += lb[(size_t)(s * NB + n) * HW + j];
  }
  pval_t[flat] = f2b(acc / ls);
}

// ---------------------------------------------------------------------------
// Kernel C: LDS-staged MFMA implicit-GEMM 3x3 conv (R8-proven body).
// grid (48, 4, NB) block 256, 3 blocks/CU.
// ---------------------------------------------------------------------------
template<int DIL, int RESM, int OUTM>
__global__ __launch_bounds__(256, 3)
void mconv(const u16* __restrict__ in_t, const u16* __restrict__ wtf,
           const void* __restrict__ res, void* __restrict__ out){
  __shared__ u16 Xs[3 * 64 * XROW];   // 52224 B

  const int tid  = threadIdx.x;
  const int w    = tid >> 6;
  const int lane = tid & 63;
  const int quad = lane >> 4;
  const int l15  = lane & 15;
  const int n    = blockIdx.z;
  const int y    = blockIdx.x;
  const int by   = blockIdx.y;
  const int xw   = w * 16;

  const bf16x8 bz8 = {0,0,0,0,0,0,0,0};
  #pragma unroll
  for (int yi = 0; yi < 3; ++yi){
    int ysrc = y + (yi - 1) * DIL;
    bool ok = (unsigned)ysrc < (unsigned)HH;
    #pragma unroll
    for (int pass = 0; pass < 4; ++pass){
      int ch = pass * 256 + tid;
      int x  = ch >> 4;
      int g  = ch & 15;
      bf16x8 vv = bz8;
      if (ok)
        vv = *(const bf16x8*)&in_t[((size_t)n * HW + ysrc * WW + x) * DH + g * 8];
      *(bf16x8*)&Xs[(yi * 64 + x) * XROW + g * 8] = vv;
    }
  }
  __syncthreads();

  f32x4 acc[2];
  acc[0] = (f32x4){0.f, 0.f, 0.f, 0.f};
  acc[1] = (f32x4){0.f, 0.f, 0.f, 0.f};

  #pragma unroll
  for (int tap = 0; tap < 9; ++tap){
    const int yi = tap / 3;
    const int dx = (tap % 3 - 1) * DIL;
    const int xp = xw + l15 + dx;
    const bool vx = (unsigned)xp < (unsigned)WW;
    const int xc = vx ? xp : 0;
    const u16* xrow = &Xs[(yi * 64 + xc) * XROW];
    #pragma unroll
    for (int cst = 0; cst < 4; ++cst){
      bf16x8 bf = bz8;
      if (vx) bf = *(const bf16x8*)&xrow[cst * 32 + quad * 8];
      #pragma unroll
      for (int dt = 0; dt < 2; ++dt){
        int fid = (tap * 4 + cst) * 8 + by * 2 + dt;
        bf16x8 af = *(const bf16x8*)&wtf[(size_t)fid * 512 + lane * 8];
        acc[dt] = __builtin_amdgcn_mfma_f32_16x16x32_bf16(af, bf, acc[dt], 0, 0, 0);
      }
    }
  }

  const int p = y * WW + xw + l15;
  #pragma unroll
  for (int dt = 0; dt < 2; ++dt){
    const int d0q = by * 32 + dt * 16 + quad * 4;
    float v4[4];
    #pragma unroll
    for (int r = 0; r < 4; ++r){
      float vv = acc[dt][r];
      vv = (vv >= 0.f) ? vv : 0.2f * vv;
      if (RESM == 1)
        vv += ((const float*)res)[((size_t)n * DH + d0q + r) * HW + p];
      v4[r] = vv;
    }
    if (RESM == 2){
      b16x4 rv = *(const b16x4*)&((const u16*)res)[((size_t)n * HW + p) * DH + d0q];
      #pragma unroll
      for (int r = 0; r < 4; ++r) v4[r] += b2f((u16)rv[r]);
    }
    if (OUTM == 0){
      b16x4 pk = { (short)f2b(v4[0]), (short)f2b(v4[1]),
                   (short)f2b(v4[2]), (short)f2b(v4[3]) };
      *(b16x4*)&((u16*)out)[((size_t)n * HW + p) * DH + d0q] = pk;
    } else {
      #pragma unroll
      for (int r = 0; r < 4; ++r)
        ((float*)out)[((size_t)n * DH + d0q + r) * HW + p] = v4[r];
    }
  }
}

// ---------------------------------------------------------------------------
extern "C" void kernel_launch(void* const* d_in, const int* in_sizes, int n_in,
                              void* d_out, int out_size, void* d_ws, size_t ws_size,
                              hipStream_t stream){
  const float* k    = (const float*)d_in[0];
  const float* q    = (const float*)d_in[1];
  const float* v    = (const float*)d_in[2];
  const float* wv   = (const float*)d_in[3];
  const float* wout = (const float*)d_in[4];
  const float* wff1 = (const float*)d_in[5];
  const float* wff2 = (const float*)d_in[6];
  float* out = (float*)d_out;

  const size_t TEN  = (size_t)NB * DH * HW;    // 1,572,864
  const size_t KTEN = (size_t)NB * CKQ * HW;   // 4,718,592
  const size_t WT   = (size_t)9 * DH * DH;     // 147,456
  u8*  kt8    = (u8*)d_ws;
  u8*  qt8    = kt8 + KTEN;
  u8*  val8   = qt8 + KTEN;
  u16* wt1    = (u16*)(val8 + TEN);
  u16* wt2    = wt1 + WT;
  u16* wt3    = wt2 + WT;
  u16* pval_t = wt3 + WT;
  u16* v2_t   = pval_t + TEN;
  u16* tmid_t = v2_t + TEN;
  u16* ob     = tmid_t + TEN;                  // NSPLIT*TEN bf16
  float* lb   = (float*)(ob + (size_t)NSPLIT * TEN);

  prep   <<<dim3(984), 256, 0, stream>>>(k, q, v, wv, wout, wff1, wff2,
                                         kt8, qt8, val8, wt1, wt2, wt3);
  attn8  <<<dim3(HW / BQ, NSPLIT, NB), 256, 0, stream>>>(kt8, qt8, val8, ob, lb);
  combine<<<dim3((unsigned)(TEN / 256)), 256, 0, stream>>>(ob, lb, pval_t);
  mconv<1, 1, 0><<<dim3(48, 4, NB), 256, 0, stream>>>(pval_t, wt1, (const void*)v,    (void*)v2_t);
  mconv<2, 0, 0><<<dim3(48, 4, NB), 256, 0, stream>>>(v2_t,   wt2, (const void*)nullptr, (void*)tmid_t);
  mconv<1, 2, 1><<<dim3(48, 4, NB), 256, 0, stream>>>(tmid_t, wt3, (const void*)v2_t, (void*)out);
}